// Round 1
// baseline (16789.583 us; speedup 1.0000x reference)
//
#include <hip/hip_runtime.h>

typedef _Float16 f16;
typedef _Float16 f16x8 __attribute__((ext_vector_type(8)));
typedef float f32x4 __attribute__((ext_vector_type(4)));
typedef float f32x16 __attribute__((ext_vector_type(16)));

#define SEQ 512
#define BATCH 256
#define DIN 512
#define DH 1024
#define DK 1536
#define NCLS 1000

#define NGROUP 8      // batch groups (XCD-affine: group = blockIdx & 7)
#define WGPG 32       // workgroups per group
#define ROWS 32       // batch rows per group
#define OUTS 32       // hidden outputs per WG
#define KSLICES 96    // DK/16
#define KPW 24        // K-slices per wave (4 waves)

#define ROWBYTES (DK * 2)                    // 3072, 16B aligned
#define RED_OFF (ROWS * ROWBYTES)            // 98304
#define RED_STRIDE 33
#define RED_BYTES (4 * OUTS * RED_STRIDE * 4) // 16896
#define BIAS_OFF (RED_OFF + RED_BYTES)
#define SMEM_BYTES (BIAS_OFF + OUTS * 4)     // 115328 <= 160K LDS

// ws layout
#define WF_BYTES    ((size_t)DH * DK * 2)          // 3 MB  W in f16 frag layout
#define HBUF_OFF    WF_BYTES
#define HBUF_BYTES  ((size_t)2 * BATCH * DH * 2)   // 1 MB  double-buffered h (f16)
#define FLAGS_OFF   (HBUF_OFF + HBUF_BYTES)
#define FLAGS_BYTES ((size_t)256 * 16 * 4)         // 16 KB, 64B-spaced flags

// ---- W [1024][1536] fp32 -> f16 A-fragment-linear layout ----
// Wf[((s*96 + j)*64 + lane)*8 + v] = W[s*32 + (lane&31)][j*16 + (lane>>5)*8 + v]
__global__ void __launch_bounds__(256) convert_W_kernel(const float* __restrict__ W,
                                                        f16* __restrict__ Wf) {
    int id = blockIdx.x * 256 + threadIdx.x;
    if (id >= DH * DK) return;
    int v = id & 7;
    int l = (id >> 3) & 63;
    int rest = id >> 9;            // s*96 + j
    int j = rest % KSLICES;
    int s = rest / KSLICES;
    int row = s * OUTS + (l & 31);
    int k = j * 16 + ((l >> 5) << 3) + v;
    Wf[id] = (f16)W[row * DK + k];
}

// ---- persistent RNN kernel: 256 WGs (8 groups x 32), 256 threads each ----
__global__ void __launch_bounds__(256) rnn_kernel(const float* __restrict__ x,
                                                  const float* __restrict__ bias,
                                                  const f16* __restrict__ Wf,
                                                  f16* __restrict__ hbuf,
                                                  unsigned* __restrict__ flags) {
    extern __shared__ char smem[];
    float* red  = (float*)(smem + RED_OFF);
    float* blds = (float*)(smem + BIAS_OFF);

    const int tid  = threadIdx.x;
    const int g    = blockIdx.x & 7;   // group
    const int s    = blockIdx.x >> 3;  // out-slice 0..31
    const int wave = tid >> 6;
    const int lane = tid & 63;

    if (tid < OUTS) blds[tid] = bias[s * OUTS + tid];

    // weight fragments -> registers (96 VGPRs/lane), coalesced b128 loads
    f16x8 wf[KPW];
    {
        const f16x8* wp = ((const f16x8*)Wf) + (size_t)(s * KSLICES + wave * KPW) * 64 + lane;
#pragma unroll
        for (int jj = 0; jj < KPW; ++jj) wf[jj] = wp[jj * 64];
    }

    unsigned* myflag = flags + (size_t)blockIdx.x * 16;

    // staging assignment: thread = (row sr, segment sseg)
    const int sr   = tid >> 3;   // 0..31
    const int sseg = tid & 7;    // 0..7
    char* rowbase  = smem + sr * ROWBYTES;
    const int swz  = (sr & 7) << 4;

    // MFMA B-frag addressing
    const int r    = lane & 31;
    const int khi  = (lane >> 5) << 3;
    const int rsw  = (r & 7) << 4;
    char* fragrow  = smem + r * ROWBYTES;

    for (int t = 0; t < SEQ; ++t) {
        // ---- 1. wait: all WGs of this group done with step t-1 ----
        if (tid < WGPG) {
            unsigned* fp = flags + (size_t)(g + 8 * tid) * 16;
            while (__hip_atomic_load(fp, __ATOMIC_ACQUIRE, __HIP_MEMORY_SCOPE_AGENT) < (unsigned)t)
                __builtin_amdgcn_s_sleep(1);
        }
        __syncthreads();

        // ---- 2. stage x_t (fp32->f16) and h (f16) into swizzled LDS ----
        {
            const float* xp = x + ((size_t)t * BATCH + g * ROWS + sr) * DIN + sseg * 64;
#pragma unroll
            for (int c = 0; c < 8; ++c) {
                f32x4 a0 = *(const f32x4*)(xp + c * 8);
                f32x4 a1 = *(const f32x4*)(xp + c * 8 + 4);
                f16x8 o;
                o[0] = (f16)a0[0]; o[1] = (f16)a0[1]; o[2] = (f16)a0[2]; o[3] = (f16)a0[3];
                o[4] = (f16)a1[0]; o[5] = (f16)a1[1]; o[6] = (f16)a1[2]; o[7] = (f16)a1[3];
                int kb = (sseg * 64 + c * 8) * 2;
                *(f16x8*)(rowbase + (kb ^ swz)) = o;
            }
            const f16* hp = hbuf + ((size_t)(t & 1) * BATCH + g * ROWS + sr) * DH + sseg * 128;
#pragma unroll
            for (int c = 0; c < 16; ++c) {
                f16x8 hv = *(const f16x8*)(hp + c * 8);
                int kb = (DIN + sseg * 128 + c * 8) * 2;
                *(f16x8*)(rowbase + (kb ^ swz)) = hv;
            }
        }
        __syncthreads();

        // ---- 3. MFMA: wave's K-range, A from regs, B from LDS ----
        f32x16 acc = {0,0,0,0, 0,0,0,0, 0,0,0,0, 0,0,0,0};
#pragma unroll
        for (int jj = 0; jj < KPW; ++jj) {
            int k = (wave * KPW + jj) * 16 + khi;
            f16x8 bf = *(const f16x8*)(fragrow + ((k * 2) ^ rsw));
            acc = __builtin_amdgcn_mfma_f32_32x32x16_f16(wf[jj], bf, acc, 0, 0, 0);
        }

        // ---- 4. write K-split partials (C/D: col=lane&31, row=(v&3)+8*(v>>2)+4*(lane>>5)) ----
        {
            float* rw = red + wave * (OUTS * RED_STRIDE);
            int col = lane & 31;
            int rbase = (lane >> 5) << 2;
#pragma unroll
            for (int v = 0; v < 16; ++v) {
                int orow = (v & 3) + 8 * (v >> 2) + rbase;
                rw[orow * RED_STRIDE + col] = acc[v];
            }
        }
        __syncthreads();

        // ---- 5. finish: reduce 4 partials + bias, tanh, write h (f16) ----
        {
            int b_ = tid >> 3;
            int o0 = (tid & 7) * 4;
            f16* hout = hbuf + ((size_t)((t + 1) & 1) * BATCH + g * ROWS + b_) * DH + s * OUTS + o0;
            union { f16 h4[4]; uint2 u; } uu;
#pragma unroll
            for (int i = 0; i < 4; ++i) {
                int o = o0 + i;
                float p = blds[o];
#pragma unroll
                for (int w2 = 0; w2 < 4; ++w2)
                    p += red[w2 * (OUTS * RED_STRIDE) + o * RED_STRIDE + b_];
                uu.h4[i] = (f16)tanhf(p);
            }
            *(uint2*)hout = uu.u;
        }
        __threadfence();
        __syncthreads();
        if (tid == 0)
            __hip_atomic_store(myflag, (unsigned)(t + 1), __ATOMIC_RELEASE, __HIP_MEMORY_SCOPE_AGENT);
    }
}

// ---- classify: block per class, thread per batch row ----
__global__ void __launch_bounds__(256) classify_kernel(const f16* __restrict__ h,
                                                       const float* __restrict__ Wc,
                                                       const float* __restrict__ bc,
                                                       float* __restrict__ out) {
    __shared__ float wrow[DH];
    int c = blockIdx.x;
    int tid = threadIdx.x;
    for (int i = tid; i < DH; i += 256) wrow[i] = Wc[(size_t)c * DH + i];
    __syncthreads();
    const f16* hrow = h + (size_t)tid * DH;
    float acc = bc[c];
#pragma unroll 4
    for (int k = 0; k < DH; k += 8) {
        f16x8 hv = *(const f16x8*)(hrow + k);
#pragma unroll
        for (int i2 = 0; i2 < 8; ++i2) acc += (float)hv[i2] * wrow[k + i2];
    }
    out[(size_t)tid * NCLS + c] = acc;
}

extern "C" void kernel_launch(void* const* d_in, const int* in_sizes, int n_in,
                              void* d_out, int out_size, void* d_ws, size_t ws_size,
                              hipStream_t stream) {
    const float* x  = (const float*)d_in[0];
    const float* W  = (const float*)d_in[1];
    const float* b  = (const float*)d_in[2];
    const float* Wc = (const float*)d_in[3];
    const float* bc = (const float*)d_in[4];
    float* out = (float*)d_out;

    char* ws = (char*)d_ws;
    f16* Wf        = (f16*)ws;
    f16* hbuf      = (f16*)(ws + HBUF_OFF);
    unsigned* flags = (unsigned*)(ws + FLAGS_OFF);

    // h0 = 0 (buffer 0), flags = 0
    hipMemsetAsync(hbuf, 0, (size_t)BATCH * DH * 2, stream);
    hipMemsetAsync(flags, 0, FLAGS_BYTES, stream);

    convert_W_kernel<<<(DH * DK + 255) / 256, 256, 0, stream>>>(W, Wf);

    hipFuncSetAttribute((const void*)rnn_kernel,
                        hipFuncAttributeMaxDynamicSharedMemorySize, SMEM_BYTES);
    void* args[5];
    args[0] = (void*)&x;
    args[1] = (void*)&b;
    args[2] = (void*)&Wf;
    args[3] = (void*)&hbuf;
    args[4] = (void*)&flags;
    hipLaunchCooperativeKernel((const void*)rnn_kernel, dim3(256), dim3(256),
                               args, SMEM_BYTES, stream);

    // final h is in hbuf[0] (step 511 writes buffer (512)&1 = 0)
    classify_kernel<<<dim3(NCLS), dim3(256), 0, stream>>>(hbuf, Wc, bc, out);
}

// Round 2
// 3780.941 us; speedup vs baseline: 4.4406x; 4.4406x over previous
//
#include <hip/hip_runtime.h>

typedef _Float16 f16;
typedef _Float16 f16x8 __attribute__((ext_vector_type(8)));
typedef float f32x4 __attribute__((ext_vector_type(4)));
typedef float f32x16 __attribute__((ext_vector_type(16)));

#define SEQ 512
#define BATCH 256
#define DIN 512
#define DH 1024
#define DK 1536
#define NCLS 1000

#define NGROUP 8      // batch groups (one per XCD by blockIdx&7 round-robin; perf-only)
#define WGPG 32       // workgroups per group
#define ROWS 32       // batch rows per group
#define OUTS 32       // hidden outputs per WG
#define KSLICES 96    // DK/16
#define RED_STRIDE 33

// ws layout
#define WF_BYTES    ((size_t)DH * DK * 2)          // 3 MB  W in f16 frag layout
#define HBUF_OFF    WF_BYTES
#define HBUF_BYTES  ((size_t)2 * BATCH * DH * 2)   // 1 MB  double-buffered h (f16)
#define FLAGS_OFF   (HBUF_OFF + HBUF_BYTES)
#define FLAGS_BYTES ((size_t)256 * 16 * 4)         // 16 KB, 64B-spaced flags

// ---- L3-coherent (bypass L1+L2) access helpers: sc0 sc1 ----
__device__ __forceinline__ unsigned flag_load(const unsigned* p) {
    unsigned v;
    asm volatile("global_load_dword %0, %1, off sc0 sc1\n\ts_waitcnt vmcnt(0)"
                 : "=v"(v) : "v"(p) : "memory");
    return v;
}
__device__ __forceinline__ void flag_store(unsigned* p, unsigned v) {
    asm volatile("global_store_dword %0, %1, off sc0 sc1" :: "v"(p), "v"(v) : "memory");
}
__device__ __forceinline__ f16x8 hload(const f16* p) {
    f16x8 v;
    asm volatile("global_load_dwordx4 %0, %1, off sc0 sc1" : "=v"(v) : "v"(p) : "memory");
    return v;
}
__device__ __forceinline__ void hstore(f16* p, uint2 v) {
    asm volatile("global_store_dwordx2 %0, %1, off sc0 sc1" :: "v"(p), "v"(v) : "memory");
}

// ---- W [1024][1536] fp32 -> f16 A-fragment-linear layout ----
// Wf[((s*96 + j)*64 + lane)*8 + v] = W[s*32 + (lane&31)][j*16 + (lane>>5)*8 + v]
__global__ void __launch_bounds__(256) convert_W_kernel(const float* __restrict__ W,
                                                        f16* __restrict__ Wf) {
    int id = blockIdx.x * 256 + threadIdx.x;
    if (id >= DH * DK) return;
    int v = id & 7;
    int l = (id >> 3) & 63;
    int rest = id >> 9;            // s*96 + j
    int j = rest % KSLICES;
    int s = rest / KSLICES;
    int row = s * OUTS + (l & 31);
    int k = j * 16 + ((l >> 5) << 3) + v;
    Wf[id] = (f16)W[row * DK + k];
}

// ---- persistent RNN kernel: 256 WGs (8 groups x 32), 256 threads each ----
// Wave w owns K-slices j with j%4==w: 8 x-slices (j<32) + 16 h-slices (j>=32).
// No LDS staging: B-fragments load straight from global (x cached; h via L3).
__global__ void __launch_bounds__(256, 1) rnn_kernel(const float* __restrict__ x,
                                                     const float* __restrict__ bias,
                                                     const f16* __restrict__ Wf,
                                                     f16* __restrict__ hbuf,
                                                     unsigned* __restrict__ flags) {
    __shared__ float red[4 * OUTS * RED_STRIDE];
    __shared__ float blds[OUTS];

    const int tid  = threadIdx.x;
    const int g    = blockIdx.x & 7;   // group
    const int s    = blockIdx.x >> 3;  // out-slice 0..31
    const int wave = tid >> 6;
    const int lane = tid & 63;
    const int r    = lane & 31;        // batch row within group / MFMA B col
    const int hi   = lane >> 5;        // K-half within slice

    if (tid < OUTS) blds[tid] = bias[s * OUTS + tid];

    // weight A-fragments -> registers (96 VGPRs/lane)
    f16x8 wf[24];
    {
        const f16x8* wp = ((const f16x8*)Wf) + (size_t)s * KSLICES * 64 + lane;
#pragma unroll
        for (int i = 0; i < 24; ++i) wf[i] = wp[(size_t)(wave + 4 * i) * 64];
    }

    unsigned* myflag = flags + (size_t)blockIdx.x * 16;

    // finish-phase assignment: thread = (batch row b_, 4-output chunk o0)
    const int b_ = tid >> 3;
    const int o0 = (tid & 7) * 4;

    for (int t = 0; t < SEQ; ++t) {
        f32x16 acc = {0,0,0,0, 0,0,0,0, 0,0,0,0, 0,0,0,0};

        // ---- 1. x-part (independent of h; runs while other WGs finish t-1) ----
        {
            const float* xrow = x + ((size_t)t * BATCH + g * ROWS + r) * DIN + hi * 8;
#pragma unroll
            for (int i = 0; i < 8; ++i) {
                const float* xp = xrow + (wave + 4 * i) * 16;
                f32x4 a0 = *(const f32x4*)xp;
                f32x4 a1 = *(const f32x4*)(xp + 4);
                f16x8 bf;
                bf[0] = (f16)a0[0]; bf[1] = (f16)a0[1]; bf[2] = (f16)a0[2]; bf[3] = (f16)a0[3];
                bf[4] = (f16)a1[0]; bf[5] = (f16)a1[1]; bf[6] = (f16)a1[2]; bf[7] = (f16)a1[3];
                acc = __builtin_amdgcn_mfma_f32_32x32x16_f16(wf[i], bf, acc, 0, 0, 0);
            }
        }

        // ---- 2. wait: all WGs of this group done with step t-1 (relaxed L3 poll) ----
        if (lane < WGPG) {
            const unsigned* fp = flags + (size_t)(g + 8 * lane) * 16;
            unsigned v = flag_load(fp);
            while (v < (unsigned)t) v = flag_load(fp);
        }

        // ---- 3. h-part: B-fragments straight from L3 ----
        {
            const f16* hrow = hbuf + ((size_t)(t & 1) * BATCH + g * ROWS + r) * DH + hi * 8;
            f16x8 hv[16];
#pragma unroll
            for (int i = 0; i < 16; ++i)
                hv[i] = hload(hrow + wave * 16 + 64 * i);
            asm volatile("s_waitcnt vmcnt(0)" ::: "memory");
            __builtin_amdgcn_sched_barrier(0);
#pragma unroll
            for (int i = 0; i < 16; ++i)
                acc = __builtin_amdgcn_mfma_f32_32x32x16_f16(wf[8 + i], hv[i], acc, 0, 0, 0);
        }

        // ---- 4. write K-split partials (C/D: col=lane&31, row=(v&3)+8*(v>>2)+4*(lane>>5)) ----
        {
            float* rw = red + wave * (OUTS * RED_STRIDE);
            int rbase = hi << 2;
#pragma unroll
            for (int v = 0; v < 16; ++v) {
                int orow = (v & 3) + 8 * (v >> 2) + rbase;
                rw[orow * RED_STRIDE + r] = acc[v];
            }
        }
        __syncthreads();

        // ---- 5. finish: reduce 4 partials + bias, fast tanh, write h via L3 ----
        {
            f16* hout = hbuf + ((size_t)((t + 1) & 1) * BATCH + g * ROWS + b_) * DH + s * OUTS + o0;
            union { f16 h4[4]; uint2 u; } uu;
#pragma unroll
            for (int i = 0; i < 4; ++i) {
                int o = o0 + i;
                float p = blds[o];
#pragma unroll
                for (int w2 = 0; w2 < 4; ++w2)
                    p += red[w2 * (OUTS * RED_STRIDE) + o * RED_STRIDE + b_];
                // tanh(p) = 1 - 2/(e^{2p}+1); exact at +-inf, ~1e-7 rel err
                float e = __expf(2.f * p);
                uu.h4[i] = (f16)(1.f - 2.f / (e + 1.f));
            }
            hstore(hout, uu.u);
        }
        asm volatile("s_waitcnt vmcnt(0)" ::: "memory");  // per-wave: h stores reached L3
        __syncthreads();                                   // all waves drained
        if (tid == 0) flag_store(myflag, (unsigned)(t + 1));
        __syncthreads();  // keep red[] safe until everyone passed finish
    }
}

// ---- classify: block per class, thread per batch row ----
__global__ void __launch_bounds__(256) classify_kernel(const f16* __restrict__ h,
                                                       const float* __restrict__ Wc,
                                                       const float* __restrict__ bc,
                                                       float* __restrict__ out) {
    __shared__ float wrow[DH];
    int c = blockIdx.x;
    int tid = threadIdx.x;
    for (int i = tid; i < DH; i += 256) wrow[i] = Wc[(size_t)c * DH + i];
    __syncthreads();
    const f16* hrow = h + (size_t)tid * DH;
    float acc = bc[c];
#pragma unroll 4
    for (int k = 0; k < DH; k += 8) {
        f16x8 hv = *(const f16x8*)(hrow + k);
#pragma unroll
        for (int i2 = 0; i2 < 8; ++i2) acc += (float)hv[i2] * wrow[k + i2];
    }
    out[(size_t)tid * NCLS + c] = acc;
}

extern "C" void kernel_launch(void* const* d_in, const int* in_sizes, int n_in,
                              void* d_out, int out_size, void* d_ws, size_t ws_size,
                              hipStream_t stream) {
    const float* x  = (const float*)d_in[0];
    const float* W  = (const float*)d_in[1];
    const float* b  = (const float*)d_in[2];
    const float* Wc = (const float*)d_in[3];
    const float* bc = (const float*)d_in[4];
    float* out = (float*)d_out;

    char* ws = (char*)d_ws;
    f16* Wf         = (f16*)ws;
    f16* hbuf       = (f16*)(ws + HBUF_OFF);
    unsigned* flags = (unsigned*)(ws + FLAGS_OFF);

    // h0 = 0 (buffer 0), flags = 0 — every call (graph replays re-run these)
    hipMemsetAsync(hbuf, 0, (size_t)BATCH * DH * 2, stream);
    hipMemsetAsync(flags, 0, FLAGS_BYTES, stream);

    convert_W_kernel<<<(DH * DK + 255) / 256, 256, 0, stream>>>(W, Wf);

    void* args[5];
    args[0] = (void*)&x;
    args[1] = (void*)&b;
    args[2] = (void*)&Wf;
    args[3] = (void*)&hbuf;
    args[4] = (void*)&flags;
    hipLaunchCooperativeKernel((const void*)rnn_kernel, dim3(256), dim3(256),
                               args, 0, stream);

    // final h is in hbuf[0] (step 511 writes buffer (512)&1 = 0)
    classify_kernel<<<dim3(NCLS), dim3(256), 0, stream>>>(hbuf, Wc, bc, out);
}

// Round 3
// 2720.886 us; speedup vs baseline: 6.1706x; 1.3896x over previous
//
#include <hip/hip_runtime.h>

typedef _Float16 f16;
typedef _Float16 f16x8 __attribute__((ext_vector_type(8)));
typedef float f32x4 __attribute__((ext_vector_type(4)));
typedef float f32x16 __attribute__((ext_vector_type(16)));
typedef unsigned int u32;
typedef u32 u32x4 __attribute__((ext_vector_type(4)));

#define SEQ 512
#define BATCH 256
#define DIN 512
#define DH 1024
#define DK 1536
#define NCLS 1000

#define NGROUP 8      // batch groups (XCD round-robin by blockIdx&7; perf heuristic only)
#define WGPG 32       // workgroups per group
#define ROWS 32       // batch rows per group
#define OUTS 32       // hidden outputs per WG
#define KSLICES 96    // DK/16
#define RED_STRIDE 33

// ws layout
#define WF_BYTES    ((size_t)DH * DK * 2)          // 3 MB  W in f16 frag layout
#define HBUF_OFF    WF_BYTES
#define HBUF_HALF   ((size_t)BATCH * DH * 2)       // 512 KB per buffer
#define HBUF_BYTES  (2 * HBUF_HALF)

// tag bit: f16 bit14 (0x4000). tanh output |h|<=1 -> bit14 always 0 in real data.
#define TAGBITS 0x40004000u
#define STRIPM  0xBFFFBFFFu

// ---- L3-coherent (bypass L1+L2) access helpers: sc0 sc1 ----
__device__ __forceinline__ u32x4 hload4(const void* p) {
    u32x4 v;
    asm volatile("global_load_dwordx4 %0, %1, off sc0 sc1" : "=v"(v) : "v"(p) : "memory");
    return v;
}
__device__ __forceinline__ void hstore8(void* p, uint2 v) {
    asm volatile("global_store_dwordx2 %0, %1, off sc0 sc1" :: "v"(p), "v"(v) : "memory");
}

// ---- W [1024][1536] fp32 -> f16 A-fragment-linear layout ----
// Wf[((s*96 + j)*64 + lane)*8 + v] = W[s*32 + (lane&31)][j*16 + (lane>>5)*8 + v]
__global__ void __launch_bounds__(256) convert_W_kernel(const float* __restrict__ W,
                                                        f16* __restrict__ Wf) {
    int id = blockIdx.x * 256 + threadIdx.x;
    if (id >= DH * DK) return;
    int v = id & 7;
    int l = (id >> 3) & 63;
    int rest = id >> 9;            // s*96 + j
    int j = rest % KSLICES;
    int s = rest / KSLICES;
    int row = s * OUTS + (l & 31);
    int k = j * 16 + ((l >> 5) << 3) + v;
    Wf[id] = (f16)W[row * DK + k];
}

// ---- persistent RNN kernel: 256 WGs (8 groups x 32), 256 threads each ----
// Wave w owns K-slices j with j%4==w: 8 x-slices (j<32) + 16 h-slices (j>=32).
// h exchange: tagged data through L3 (sc0 sc1). No flags, no fences.
__global__ void __launch_bounds__(256, 1) rnn_kernel(const float* __restrict__ x,
                                                     const float* __restrict__ bias,
                                                     const f16* __restrict__ Wf,
                                                     f16* __restrict__ hbuf) {
    __shared__ float red[4 * OUTS * RED_STRIDE];
    __shared__ float blds[OUTS];

    const int tid  = threadIdx.x;
    const int g    = blockIdx.x & 7;   // group
    const int s    = blockIdx.x >> 3;  // out-slice 0..31
    const int wave = tid >> 6;
    const int lane = tid & 63;
    const int r    = lane & 31;        // batch row within group / MFMA B col
    const int hi   = lane >> 5;        // K-half within slice

    if (tid < OUTS) blds[tid] = bias[s * OUTS + tid];

    // weight A-fragments -> registers
    f16x8 wf[24];
    {
        const f16x8* wp = ((const f16x8*)Wf) + (size_t)s * KSLICES * 64 + lane;
#pragma unroll
        for (int i = 0; i < 24; ++i) wf[i] = wp[(size_t)(wave + 4 * i) * 64];
    }

    // finish-phase assignment: thread = (batch row b_, 4-output chunk o0)
    const int b_ = tid >> 3;
    const int o0 = (tid & 7) * 4;

    for (int t = 0; t < SEQ; ++t) {
        f32x16 acc = {0,0,0,0, 0,0,0,0, 0,0,0,0, 0,0,0,0};

        // ---- 1. x-part (independent of h; overlap window for stragglers) ----
        {
            const float* xrow = x + ((size_t)t * BATCH + g * ROWS + r) * DIN + hi * 8;
#pragma unroll
            for (int i = 0; i < 8; ++i) {
                const float* xp = xrow + (wave + 4 * i) * 16;
                f32x4 a0 = *(const f32x4*)xp;
                f32x4 a1 = *(const f32x4*)(xp + 4);
                f16x8 bf;
                bf[0] = (f16)a0[0]; bf[1] = (f16)a0[1]; bf[2] = (f16)a0[2]; bf[3] = (f16)a0[3];
                bf[4] = (f16)a1[0]; bf[5] = (f16)a1[1]; bf[6] = (f16)a1[2]; bf[7] = (f16)a1[3];
                acc = __builtin_amdgcn_mfma_f32_32x32x16_f16(wf[i], bf, acc, 0, 0, 0);
            }
        }

        // ---- 2. h-part: poll the tagged data itself (the data IS the flag) ----
        {
            const char* hrb = (const char*)(hbuf + ((size_t)(t & 1) * BATCH + g * ROWS + r) * DH
                                            + hi * 8) + wave * 32;
            const u32 rtag = (u32)((t >> 1) & 1);   // expected generation tag
            u32x4 hv[16];
            if (rtag == 0) {
                for (;;) {
#pragma unroll
                    for (int i = 0; i < 16; ++i) hv[i] = hload4(hrb + i * 128);
                    asm volatile("s_waitcnt vmcnt(0)" ::: "memory");
                    u32 orr = 0;
#pragma unroll
                    for (int i = 0; i < 16; ++i) orr |= hv[i].x | hv[i].y | hv[i].z | hv[i].w;
                    if (__all((orr & TAGBITS) == 0u)) break;
                }
            } else {
                for (;;) {
#pragma unroll
                    for (int i = 0; i < 16; ++i) hv[i] = hload4(hrb + i * 128);
                    asm volatile("s_waitcnt vmcnt(0)" ::: "memory");
                    u32 andv = 0xFFFFFFFFu;
#pragma unroll
                    for (int i = 0; i < 16; ++i) andv &= hv[i].x & hv[i].y & hv[i].z & hv[i].w;
                    if (__all((andv & TAGBITS) == TAGBITS)) break;
                }
#pragma unroll
                for (int i = 0; i < 16; ++i) hv[i] &= STRIPM;   // strip tag bits
            }
            union cvt_t { u32x4 u; f16x8 h; };
#pragma unroll
            for (int i = 0; i < 16; ++i) {
                cvt_t c; c.u = hv[i];
                acc = __builtin_amdgcn_mfma_f32_32x32x16_f16(wf[8 + i], c.h, acc, 0, 0, 0);
            }
        }

        // ---- 3. write K-split partials (C/D: col=lane&31, row=(v&3)+8*(v>>2)+4*hi) ----
        {
            float* rw = red + wave * (OUTS * RED_STRIDE);
            int rbase = hi << 2;
#pragma unroll
            for (int v = 0; v < 16; ++v) {
                int orow = (v & 3) + 8 * (v >> 2) + rbase;
                rw[orow * RED_STRIDE + r] = acc[v];
            }
        }
        __syncthreads();

        // ---- 4. finish: reduce 4 partials + bias, fast tanh, tagged store ----
        {
            const u32 wtag = (u32)(((t + 1) >> 1) & 1);
            f16* hout = hbuf + ((size_t)((t + 1) & 1) * BATCH + g * ROWS + b_) * DH + s * OUTS + o0;
            union { f16 h4[4]; uint2 u; } uu;
#pragma unroll
            for (int i = 0; i < 4; ++i) {
                int o = o0 + i;
                float p = blds[o];
#pragma unroll
                for (int w2 = 0; w2 < 4; ++w2)
                    p += red[w2 * (OUTS * RED_STRIDE) + o * RED_STRIDE + b_];
                // tanh(p) = 1 - 2/(e^{2p}+1); |result| <= 1 so f16 bit14 == 0
                float e = __expf(2.f * p);
                uu.h4[i] = (f16)(1.f - 2.f / (e + 1.f));
            }
            if (wtag) { uu.u.x |= TAGBITS; uu.u.y |= TAGBITS; }
            hstore8(hout, uu.u);
        }
        __syncthreads();   // red[] safe for next step
    }
}

// ---- classify: block per class, thread per batch row ----
__global__ void __launch_bounds__(256) classify_kernel(const f16* __restrict__ h,
                                                       const float* __restrict__ Wc,
                                                       const float* __restrict__ bc,
                                                       float* __restrict__ out) {
    __shared__ float wrow[DH];
    int c = blockIdx.x;
    int tid = threadIdx.x;
    for (int i = tid; i < DH; i += 256) wrow[i] = Wc[(size_t)c * DH + i];
    __syncthreads();
    const f16* hrow = h + (size_t)tid * DH;
    float acc = bc[c];
#pragma unroll 4
    for (int k = 0; k < DH; k += 8) {
        f16x8 hv = *(const f16x8*)(hrow + k);
#pragma unroll
        for (int i2 = 0; i2 < 8; ++i2) acc += (float)hv[i2] * wrow[k + i2];
    }
    out[(size_t)tid * NCLS + c] = acc;
}

extern "C" void kernel_launch(void* const* d_in, const int* in_sizes, int n_in,
                              void* d_out, int out_size, void* d_ws, size_t ws_size,
                              hipStream_t stream) {
    const float* x  = (const float*)d_in[0];
    const float* W  = (const float*)d_in[1];
    const float* b  = (const float*)d_in[2];
    const float* Wc = (const float*)d_in[3];
    const float* bc = (const float*)d_in[4];
    float* out = (float*)d_out;

    char* ws = (char*)d_ws;
    f16* Wf   = (f16*)ws;
    f16* hbuf = (f16*)(ws + HBUF_OFF);

    // buffer 0: zeros = h0, valid for tag 0.  buffer 1: 0x4040 pattern = stale
    // (bit14 set) for the first tag-0 read at t=1.  Re-done every call.
    hipMemsetAsync(hbuf, 0, HBUF_HALF, stream);
    hipMemsetAsync((char*)hbuf + HBUF_HALF, 0x40, HBUF_HALF, stream);

    convert_W_kernel<<<(DH * DK + 255) / 256, 256, 0, stream>>>(W, Wf);

    void* args[4];
    args[0] = (void*)&x;
    args[1] = (void*)&b;
    args[2] = (void*)&Wf;
    args[3] = (void*)&hbuf;
    hipLaunchCooperativeKernel((const void*)rnn_kernel, dim3(256), dim3(256),
                               args, 0, stream);

    // final h is in hbuf[0] (step 511 writes buffer (512)&1 = 0, tag 0 = clean)
    classify_kernel<<<dim3(NCLS), dim3(256), 0, stream>>>(hbuf, Wc, bc, out);
}